// Round 6
// baseline (1233.769 us; speedup 1.0000x reference)
//
#include <hip/hip_runtime.h>
#include <cstdint>
#include <cstddef>

#define HD 128
#define EDGED 16
#define NODED 64
#define LN_EPS 1e-5f

typedef __bf16 bf16x8 __attribute__((ext_vector_type(8)));
typedef float  f32x4  __attribute__((ext_vector_type(4)));

__device__ __forceinline__ float gelu_exact(float x) {
    return 0.5f * x * (1.0f + erff(x * 0.7071067811865475f));
}

// fp32 -> bf16 hi/lo split (a ~= hi + lo, lo captures the rounding residual)
__global__ void wconv_k(const float* __restrict__ in, __bf16* __restrict__ hi,
                        __bf16* __restrict__ lo, int n) {
    int i = blockIdx.x * blockDim.x + threadIdx.x;
    if (i < n) {
        float v = in[i];
        __bf16 h = (__bf16)v;
        hi[i] = h;
        lo[i] = (__bf16)(v - (float)h);
    }
}

// ---------------- CSR build ----------------

__global__ void hist_k(const int* __restrict__ ei, int* __restrict__ cnt, int E) {
    int e = blockIdx.x * blockDim.x + threadIdx.x;
    if (e < E) atomicAdd(&cnt[ei[E + e]], 1);
}

__global__ void scan1_k(const int* __restrict__ in, int* __restrict__ out,
                        int* __restrict__ bsum, int n) {
    __shared__ int lds[256];
    int t = threadIdx.x;
    int i = blockIdx.x * 256 + t;
    int v = (i < n) ? in[i] : 0;
    lds[t] = v;
    __syncthreads();
#pragma unroll
    for (int o = 1; o < 256; o <<= 1) {
        int u = (t >= o) ? lds[t - o] : 0;
        __syncthreads();
        lds[t] += u;
        __syncthreads();
    }
    if (i < n) out[i] = lds[t] - v;
    if (t == 255) bsum[blockIdx.x] = lds[255];
}

__global__ void scan2_k(const int* __restrict__ bsum, int* __restrict__ boff, int nb) {
    __shared__ int lds[256];
    int t = threadIdx.x;
    int v = (t < nb) ? bsum[t] : 0;
    lds[t] = v;
    __syncthreads();
#pragma unroll
    for (int o = 1; o < 256; o <<= 1) {
        int u = (t >= o) ? lds[t - o] : 0;
        __syncthreads();
        lds[t] += u;
        __syncthreads();
    }
    if (t < nb) boff[t] = lds[t] - v;
}

__global__ void scan3_k(int* __restrict__ rs, const int* __restrict__ boff, int n, int E) {
    int i = blockIdx.x * 256 + threadIdx.x;
    if (i < n) rs[i] += boff[blockIdx.x];
    if (i == 0) rs[n] = E;
}

__global__ void scatter_k(const int* __restrict__ ei, int* __restrict__ cursor,
                          int2* __restrict__ es, int E) {
    int e = blockIdx.x * blockDim.x + threadIdx.x;
    if (e < E) {
        int dst = ei[E + e];
        int slot = atomicAdd(&cursor[dst], 1);
        es[slot] = make_int2(ei[e], e);
    }
}

// ---------------- edge-LN precompute ----------------
// Per layer l: wm[k]=mean_c W[c][k]; bm=mean(b); Wp=W-wm; bp=b-bm.
// bg[c] = bp[c]*g[c]
// M[k][j] = sum_c Wp[c][k]*Wp[c][j]; v[k]=2*sum_c Wp[c][k]*bp[c]; s0=sum bp^2
// => 128*var(attr a) = a^T M a + v.a + s0 (no 128-wide reduce per edge).
// Also emits gamma-folded Wg in bf16 hi/lo pre-swizzled MFMA B-frag layout:
// frag idx i = tt*512 + lane*8 + j ; k=(lane>>4)*8+j (zero for k>=16), c=tt*16+(lane&15)
__global__ void prep_k(const float* __restrict__ edge_W, const float* __restrict__ edge_b,
                       const float* __restrict__ edge_g, __bf16* __restrict__ Wgfh,
                       __bf16* __restrict__ Wgfl, float* __restrict__ bg3,
                       float* __restrict__ M3, float* __restrict__ v3,
                       float* __restrict__ s03)
{
    const int l = blockIdx.x;
    const float* W = edge_W + (size_t)l * HD * EDGED;
    const float* b = edge_b + l * HD;
    const float* g = edge_g + l * HD;
    __shared__ float Wp[HD * EDGED];
    __shared__ float bp[HD];
    __shared__ float wm[EDGED];
    __shared__ float bmS;
    const int t = threadIdx.x;
#pragma unroll
    for (int m = 0; m < 8; ++m) Wp[m * 256 + t] = W[m * 256 + t];
    __syncthreads();
    if (t < EDGED) {
        float s = 0.f;
        for (int c = 0; c < HD; ++c) s += Wp[c * EDGED + t];
        wm[t] = s * (1.f / HD);
    } else if (t == EDGED) {
        float s = 0.f;
        for (int c = 0; c < HD; ++c) s += b[c];
        bmS = s * (1.f / HD);
    }
    __syncthreads();
    if (t < HD) bp[t] = b[t] - bmS;
    __syncthreads();
#pragma unroll
    for (int m = 0; m < 8; ++m) {
        int idx = m * 256 + t;
        int k = idx & 15;
        Wp[idx] = Wp[idx] - wm[k];
    }
    if (t < HD) bg3[l * HD + t] = bp[t] * g[t];
    __syncthreads();
    {
        int k = t >> 4, j = t & 15;
        float s = 0.f;
        for (int c = 0; c < HD; ++c) s += Wp[c * EDGED + k] * Wp[c * EDGED + j];
        M3[l * 256 + t] = s;
    }
    if (t < EDGED) {
        float s = 0.f;
        for (int c = 0; c < HD; ++c) s += Wp[c * EDGED + t] * bp[c];
        v3[l * EDGED + t] = 2.f * s;
    } else if (t == EDGED) {
        float s = 0.f;
        for (int c = 0; c < HD; ++c) s += bp[c] * bp[c];
        s03[l] = s;
    }
    // B-fragment swizzle (after Wp is final; no further Wp writes above)
    for (int i = t; i < 4096; i += 256) {
        int j  = i & 7;
        int ln = (i >> 3) & 63;
        int tt = i >> 9;
        int k  = (ln >> 4) * 8 + j;
        int c  = tt * 16 + (ln & 15);
        float val = (k < EDGED) ? Wp[c * EDGED + k] * g[c] : 0.f;
        __bf16 hh = (__bf16)val;
        Wgfh[(size_t)l * 4096 + i] = hh;
        Wgfl[(size_t)l * 4096 + i] = (__bf16)(val - (float)hh);
    }
}

// Per CSR slot: gather attr row once, emit rsqrt(var+eps) for all 3 layers
__launch_bounds__(256)
__global__ void einv_k(const int2* __restrict__ es, const float* __restrict__ eattr,
                       const float* __restrict__ M3, const float* __restrict__ v3,
                       const float* __restrict__ s03, float* __restrict__ einv, int E)
{
    __shared__ float Ms[3 * 256];
    __shared__ float vs[3 * 16];
    __shared__ float s0s[4];
    const int t = threadIdx.x;
    for (int i = t; i < 768; i += 256) Ms[i] = M3[i];
    if (t < 48) vs[t] = v3[t];
    if (t < 3) s0s[t] = s03[t];
    __syncthreads();
    int slot = blockIdx.x * 256 + t;
    if (slot >= E) return;
    int eid = es[slot].y;
    const float4* ap = (const float4*)(eattr + (size_t)eid * EDGED);
    float4 A0 = ap[0], A1 = ap[1], A2 = ap[2], A3 = ap[3];
    float a[16] = {A0.x, A0.y, A0.z, A0.w, A1.x, A1.y, A1.z, A1.w,
                   A2.x, A2.y, A2.z, A2.w, A3.x, A3.y, A3.z, A3.w};
#pragma unroll
    for (int l = 0; l < 3; ++l) {
        float q = s0s[l];
#pragma unroll
        for (int k = 0; k < 16; ++k) {
            const float* Mr = &Ms[l * 256 + k * 16];
            float tk = vs[l * 16 + k];
#pragma unroll
            for (int j = 0; j < 16; ++j) tk = fmaf(Mr[j], a[j], tk);
            q = fmaf(a[k], tk, q);
        }
        einv[(size_t)l * E + slot] = rsqrtf(q * (1.f / HD) + LN_EPS);
    }
}

// ---------------- MFMA GEMM, split-bf16 (bf16x3 ~ fp32 accuracy) ------------
// 16 rows/wave, 64 rows/block -> (M+63)/64 blocks (~3/CU at M=50000) for
// occupancy; wave covers all NC cols. acc = hi*hi + hi*lo + lo*hi.
template<int K, int NC, int ACT, int STATS>
__launch_bounds__(256)
__global__ void mgemm_k(const float* __restrict__ A, const __bf16* __restrict__ Whi,
                        const __bf16* __restrict__ Wlo, const float* __restrict__ bias,
                        float* __restrict__ C, int M, float* __restrict__ stats)
{
    constexpr int NT = NC / 16;
    __shared__ float st_lds[2][256];

    const int t    = threadIdx.x;
    const int lane = t & 63;
    const int wv   = t >> 6;
    const int ln15 = lane & 15;
    const int quad = lane >> 4;
    const int row_base = blockIdx.x * 64 + wv * 16;

    f32x4 acc[NT];
#pragma unroll
    for (int nt = 0; nt < NT; ++nt)
#pragma unroll
        for (int r = 0; r < 4; ++r) acc[nt][r] = 0.f;

    for (int kc = 0; kc < K; kc += 32) {
        bf16x8 ahi, alo;
        int row = row_base + ln15;
        float4 a0 = make_float4(0.f, 0.f, 0.f, 0.f), a1 = a0;
        if (row < M) {
            const float* p = A + (size_t)row * K + kc + quad * 8;
            a0 = *(const float4*)p;
            a1 = *(const float4*)(p + 4);
        }
        float av[8] = {a0.x, a0.y, a0.z, a0.w, a1.x, a1.y, a1.z, a1.w};
#pragma unroll
        for (int j = 0; j < 8; ++j) {
            __bf16 hh = (__bf16)av[j];
            ahi[j] = hh;
            alo[j] = (__bf16)(av[j] - (float)hh);
        }
#pragma unroll
        for (int nt = 0; nt < NT; ++nt) {
            const size_t boff = (size_t)(nt * 16 + ln15) * K + kc + quad * 8;
            bf16x8 bh = *(const bf16x8*)(Whi + boff);
            bf16x8 bl = *(const bf16x8*)(Wlo + boff);
            acc[nt] = __builtin_amdgcn_mfma_f32_16x16x32_bf16(ahi, bh, acc[nt], 0, 0, 0);
            acc[nt] = __builtin_amdgcn_mfma_f32_16x16x32_bf16(ahi, bl, acc[nt], 0, 0, 0);
            acc[nt] = __builtin_amdgcn_mfma_f32_16x16x32_bf16(alo, bh, acc[nt], 0, 0, 0);
        }
    }

    if (STATS) {
        if (t < NC) { st_lds[0][t] = 0.f; st_lds[1][t] = 0.f; }
        __syncthreads();
    }

    float bv[NT];
#pragma unroll
    for (int nt = 0; nt < NT; ++nt) bv[nt] = bias[nt * 16 + ln15];

    float s1[NT], s2[NT];
#pragma unroll
    for (int nt = 0; nt < NT; ++nt) { s1[nt] = 0.f; s2[nt] = 0.f; }

#pragma unroll
    for (int r = 0; r < 4; ++r) {
        int row = row_base + quad * 4 + r;
        if (row < M) {
#pragma unroll
            for (int nt = 0; nt < NT; ++nt) {
                float v = acc[nt][r] + bv[nt];
                if (ACT == 1) v = gelu_exact(v);
                C[(size_t)row * NC + nt * 16 + ln15] = v;
                if (STATS) { s1[nt] += v; s2[nt] += v * v; }
            }
        }
    }

    if (STATS) {
#pragma unroll
        for (int nt = 0; nt < NT; ++nt) {
            atomicAdd(&st_lds[0][nt * 16 + ln15], s1[nt]);
            atomicAdd(&st_lds[1][nt * 16 + ln15], s2[nt]);
        }
        __syncthreads();
        if (t < NC) {
            atomicAdd(&stats[t],      st_lds[0][t]);
            atomicAdd(&stats[HD + t], st_lds[1][t]);
        }
    }
}

// LayerNorm(+ReLU) over rows of 128, one wave per node
__global__ void ln_relu_k(const float* __restrict__ y, const float* __restrict__ gam,
                          const float* __restrict__ bet, float* __restrict__ h, int N)
{
    int lane = threadIdx.x & 63;
    int c0 = lane * 2;
    float2 g2 = *(const float2*)&gam[c0];
    float2 b2 = *(const float2*)&bet[c0];
    int wid = (blockIdx.x * blockDim.x + threadIdx.x) >> 6;
    int nw  = (gridDim.x * blockDim.x) >> 6;
    for (int n = wid; n < N; n += nw) {
        float2 v = *(const float2*)&y[(size_t)n * HD + c0];
        float s = v.x + v.y;
        float q = v.x * v.x + v.y * v.y;
#pragma unroll
        for (int o = 32; o > 0; o >>= 1) { s += __shfl_xor(s, o, 64); q += __shfl_xor(q, o, 64); }
        float mu  = s * (1.f / 128.f);
        float inv = rsqrtf(q * (1.f / 128.f) - mu * mu + LN_EPS);
        float2 r;
        r.x = fmaxf(fmaf((v.x - mu) * inv, g2.x, b2.x), 0.f);
        r.y = fmaxf(fmaf((v.y - mu) * inv, g2.y, b2.y), 0.f);
        *(float2*)&h[(size_t)n * HD + c0] = r;
    }
}

// one wave: embed the single learned self-loop attr -> sl_vec[128]
__global__ void sl_embed_k(const float* __restrict__ attr, const float* __restrict__ W,
                           const float* __restrict__ bias, const float* __restrict__ gam,
                           const float* __restrict__ bet, float* __restrict__ out)
{
    int lane = threadIdx.x;
    int c0 = lane * 2, c1 = c0 + 1;
    float acc0 = bias[c0], acc1 = bias[c1];
    for (int k = 0; k < EDGED; ++k) {
        float a = attr[k];
        acc0 = fmaf(a, W[c0 * EDGED + k], acc0);
        acc1 = fmaf(a, W[c1 * EDGED + k], acc1);
    }
    float s = acc0 + acc1, q = acc0 * acc0 + acc1 * acc1;
#pragma unroll
    for (int o = 32; o > 0; o >>= 1) { s += __shfl_xor(s, o, 64); q += __shfl_xor(q, o, 64); }
    float mu  = s * (1.f / 128.f);
    float inv = rsqrtf(q * (1.f / 128.f) - mu * mu + LN_EPS);
    out[c0] = fmaxf(fmaf((acc0 - mu) * inv, gam[c0], bet[c0]), 0.f);
    out[c1] = fmaxf(fmaf((acc1 - mu) * inv, gam[c1], bet[c1]), 0.f);
}

// ---------------- pull aggregation v4: MFMA edge-embed -----------------------
// One wave per node (grid-stride). Per 16-edge chunk: P[16e][128c] = attr @ Wg
// via 8 MFMA tiles (K=16 zero-padded to 32, 3-term hi/lo split). C-layout:
// ch = tt*16 + (lane&15), edge = quad*4 + r. Epilogue: v=max(P*einv+bet,0),
// masked-accumulated per tile; cross-quad shfl_xor reduce at node end.
// h-gather unrolled x4 for outstanding loads. No LDS. All shfl at full exec.
__launch_bounds__(256)
__global__ void pull4_k(const float* __restrict__ h, const int2* __restrict__ es,
                        const int* __restrict__ rs, const float* __restrict__ eattr,
                        const float* __restrict__ einv, const float* __restrict__ slv,
                        const __bf16* __restrict__ Wfh, const __bf16* __restrict__ Wfl,
                        const float* __restrict__ bg, const float* __restrict__ bet,
                        float* __restrict__ aggr, int N)
{
    const int t    = threadIdx.x;
    const int lane = t & 63;
    const int ln15 = lane & 15;
    const int quad = lane >> 4;

    bf16x8 Bhi[8], Blo[8];
#pragma unroll
    for (int tt = 0; tt < 8; ++tt) {
        Bhi[tt] = *(const bf16x8*)(Wfh + tt * 512 + lane * 8);
        Blo[tt] = *(const bf16x8*)(Wfl + tt * 512 + lane * 8);
    }
    float bgv[8], btv[8];
#pragma unroll
    for (int tt = 0; tt < 8; ++tt) {
        bgv[tt] = bg[tt * 16 + ln15];
        btv[tt] = bet[tt * 16 + ln15];
    }
    const float sl1 = slv[lane], sl2 = slv[lane + 64];

    const int wid = (blockIdx.x * 256 + t) >> 6;
    const int nw  = (gridDim.x * 256) >> 6;

    for (int n = wid; n < N; n += nw) {
        float acc1 = 0.f, acc2 = 0.f;
        float at[8];
#pragma unroll
        for (int tt = 0; tt < 8; ++tt) at[tt] = 0.f;

        const int beg = rs[n], end = rs[n + 1];
        for (int s0 = beg; s0 < end; s0 += 16) {
            int mcount = end - s0; if (mcount > 16) mcount = 16;
            int slot = s0 + ln15; if (slot > end - 1) slot = end - 1;  // clamp: valid mem, masked later
            int2  se = es[slot];
            float iv = einv[slot];

            // A-frag: lane = edge(ln15) + 16*quad; quad<2 holds attr octet, else zero
            bf16x8 ahi, alo;
#pragma unroll
            for (int j = 0; j < 8; ++j) { ahi[j] = (__bf16)0.f; alo[j] = (__bf16)0.f; }
            if (quad < 2) {
                const float* ap = eattr + (size_t)se.y * EDGED + quad * 8;
                float4 a0 = *(const float4*)ap;
                float4 a1 = *(const float4*)(ap + 4);
                float av[8] = {a0.x, a0.y, a0.z, a0.w, a1.x, a1.y, a1.z, a1.w};
#pragma unroll
                for (int j = 0; j < 8; ++j) {
                    __bf16 hh = (__bf16)av[j];
                    ahi[j] = hh;
                    alo[j] = (__bf16)(av[j] - (float)hh);
                }
            }

            float ive[4];
#pragma unroll
            for (int r = 0; r < 4; ++r) ive[r] = __shfl(iv, quad * 4 + r, 64);

#pragma unroll
            for (int tt = 0; tt < 8; ++tt) {
                f32x4 P;
#pragma unroll
                for (int r = 0; r < 4; ++r) P[r] = bgv[tt];
                P = __builtin_amdgcn_mfma_f32_16x16x32_bf16(ahi, Bhi[tt], P, 0, 0, 0);
                P = __builtin_amdgcn_mfma_f32_16x16x32_bf16(alo, Bhi[tt], P, 0, 0, 0);
                P = __builtin_amdgcn_mfma_f32_16x16x32_bf16(ahi, Blo[tt], P, 0, 0, 0);
#pragma unroll
                for (int r = 0; r < 4; ++r) {
                    float v = fmaxf(fmaf(P[r], ive[r], btv[tt]), 0.f);
                    at[tt] += (quad * 4 + r < mcount) ? v : 0.f;
                }
            }

            // h-gather, 4 edges per group for outstanding-load ILP
            for (int j0 = 0; j0 < mcount; j0 += 4) {
                int srcs[4];
#pragma unroll
                for (int k = 0; k < 4; ++k) srcs[k] = __shfl(se.x, j0 + k, 64);
                float hv1[4], hv2[4];
#pragma unroll
                for (int k = 0; k < 4; ++k) {
                    hv1[k] = h[(size_t)srcs[k] * HD + lane];
                    hv2[k] = h[(size_t)srcs[k] * HD + lane + 64];
                }
#pragma unroll
                for (int k = 0; k < 4; ++k) {
                    bool ok = (j0 + k) < mcount;
                    acc1 += ok ? hv1[k] : 0.f;
                    acc2 += ok ? hv2[k] : 0.f;
                }
            }
        }

        // cross-quad reduce: lanes {x, x^16, x^32, x^48} share (tile-col ln15)
#pragma unroll
        for (int tt = 0; tt < 8; ++tt) {
            at[tt] += __shfl_xor(at[tt], 16, 64);
            at[tt] += __shfl_xor(at[tt], 32, 64);
        }
        // channel lane = quad*16+ln15 -> tile quad; channel lane+64 -> tile quad+4
        aggr[(size_t)n * HD + lane]      = h[(size_t)n * HD + lane]      + sl1 + acc1 + at[quad];
        aggr[(size_t)n * HD + lane + 64] = h[(size_t)n * HD + lane + 64] + sl2 + acc2 + at[quad + 4];
    }
}

// BatchNorm apply from accumulated column sums; optional ReLU
__global__ void bn_k(const float* __restrict__ hl, const float* __restrict__ stats,
                     const float* __restrict__ gam, const float* __restrict__ bet,
                     float* __restrict__ out, int total4, float invN, int relu)
{
    int idx = blockIdx.x * blockDim.x + threadIdx.x;
    if (idx < total4) {
        int c4 = idx & 31;
        float4 x  = ((const float4*)hl)[idx];
        float4 s1 = ((const float4*)stats)[c4];
        float4 s2 = ((const float4*)stats)[32 + c4];
        float4 g  = ((const float4*)gam)[c4];
        float4 b  = ((const float4*)bet)[c4];
        float4 r;
        {
            float m = s1.x * invN; float v = s2.x * invN - m * m;
            r.x = fmaf((x.x - m) * rsqrtf(v + LN_EPS), g.x, b.x);
        }
        {
            float m = s1.y * invN; float v = s2.y * invN - m * m;
            r.y = fmaf((x.y - m) * rsqrtf(v + LN_EPS), g.y, b.y);
        }
        {
            float m = s1.z * invN; float v = s2.z * invN - m * m;
            r.z = fmaf((x.z - m) * rsqrtf(v + LN_EPS), g.z, b.z);
        }
        {
            float m = s1.w * invN; float v = s2.w * invN - m * m;
            r.w = fmaf((x.w - m) * rsqrtf(v + LN_EPS), g.w, b.w);
        }
        if (relu) {
            r.x = fmaxf(r.x, 0.f); r.y = fmaxf(r.y, 0.f);
            r.z = fmaxf(r.z, 0.f); r.w = fmaxf(r.w, 0.f);
        }
        ((float4*)out)[idx] = r;
    }
}

extern "C" void kernel_launch(void* const* d_in, const int* in_sizes, int n_in,
                              void* d_out, int out_size, void* d_ws, size_t ws_size,
                              hipStream_t stream)
{
    const float* x       = (const float*)d_in[0];
    const int*   ei      = (const int*)d_in[1];
    const float* eattr   = (const float*)d_in[2];
    const float* node_W  = (const float*)d_in[3];
    const float* node_b  = (const float*)d_in[4];
    const float* node_g  = (const float*)d_in[5];
    const float* node_be = (const float*)d_in[6];
    const float* edge_W  = (const float*)d_in[7];
    const float* edge_b  = (const float*)d_in[8];
    const float* edge_g  = (const float*)d_in[9];
    const float* edge_be = (const float*)d_in[10];
    const float* sl_attr = (const float*)d_in[11];
    const float* W1      = (const float*)d_in[12];
    const float* b1      = (const float*)d_in[13];
    const float* W2      = (const float*)d_in[14];
    const float* b2      = (const float*)d_in[15];
    const float* bn_g    = (const float*)d_in[16];
    const float* bn_b    = (const float*)d_in[17];

    const int N = in_sizes[0] / NODED;
    const int E = in_sizes[1] / 2;

    float* ws    = (float*)d_ws;
    float* h     = ws;                         // N*128
    float* aggr  = h    + (size_t)N * HD;      // N*128
    float* z     = aggr + (size_t)N * HD;      // N*256
    float* slv   = z    + (size_t)N * 256;     // 128
    float* stats = slv  + 128;                 // 256
    int*   cnt    = (int*)(stats + 256);         // N
    int*   cursor = cnt + N;                     // N
    int*   bsum   = cursor + N;                  // 256
    int*   boff   = bsum + 256;                  // 256
    int*   rs     = boff + 256;                  // N+2
    int2*  es     = (int2*)(rs + N + 2);         // E (8B aligned)
    float* einv   = (float*)(es + E);            // 3*E
    float* bg3    = einv + (size_t)3 * E;        // 3*128
    float* M3     = bg3 + 3 * 128;               // 3*256
    float* v3     = M3 + 3 * 256;                // 3*16
    float* s03    = v3 + 3 * 16;                 // 3 (+1 pad)
    __bf16* nWhi  = (__bf16*)(s03 + 4);          // 128*64
    __bf16* nWlo  = nWhi + HD * NODED;
    __bf16* W1hi  = nWlo + HD * NODED;           // 3*256*128
    __bf16* W1lo  = W1hi + 3 * 256 * HD;
    __bf16* W2hi  = W1lo + 3 * 256 * HD;         // 3*128*256
    __bf16* W2lo  = W2hi + 3 * HD * 256;
    __bf16* Wgfh3 = W2lo + 3 * HD * 256;         // 3*4096 (pre-swizzled B-frags)
    __bf16* Wgfl3 = Wgfh3 + 3 * 4096;

    // weight split-bf16 conversion (layouts already [N][K] row-major)
    wconv_k<<<(HD * NODED + 255) / 256, 256, 0, stream>>>(node_W, nWhi, nWlo, HD * NODED);
    wconv_k<<<(3 * 256 * HD + 255) / 256, 256, 0, stream>>>(W1, W1hi, W1lo, 3 * 256 * HD);
    wconv_k<<<(3 * 256 * HD + 255) / 256, 256, 0, stream>>>(W2, W2hi, W2lo, 3 * 256 * HD);

    // edge-LN precompute (all 3 layers)
    prep_k<<<3, 256, 0, stream>>>(edge_W, edge_b, edge_g, Wgfh3, Wgfl3, bg3, M3, v3, s03);

    // ---- CSR build ----
    const int eblocks = (E + 255) / 256;
    const int nblocks = (N + 255) / 256;
    hipMemsetAsync(cnt, 0, (size_t)N * sizeof(int), stream);
    hist_k<<<eblocks, 256, 0, stream>>>(ei, cnt, E);
    scan1_k<<<nblocks, 256, 0, stream>>>(cnt, rs, bsum, N);
    scan2_k<<<1, 256, 0, stream>>>(bsum, boff, nblocks);
    scan3_k<<<nblocks, 256, 0, stream>>>(rs, boff, N, E);
    hipMemcpyAsync(cursor, rs, (size_t)N * sizeof(int), hipMemcpyDeviceToDevice, stream);
    scatter_k<<<eblocks, 256, 0, stream>>>(ei, cursor, es, E);

    // per-slot inv-std for all 3 layers (one attr gather)
    einv_k<<<eblocks, 256, 0, stream>>>(es, eattr, M3, v3, s03, einv, E);

    const int mb      = (N + 63) / 64;
    const int total4  = N * (HD / 4);
    const int vblocks = (total4 + 255) / 256;
    const int pblocks = (N + 3) / 4;

    // node embed: Linear (MFMA) -> LN -> ReLU
    mgemm_k<NODED, HD, 0, 0><<<mb, 256, 0, stream>>>(x, nWhi, nWlo, node_b, z, N, nullptr);
    ln_relu_k<<<pblocks, 256, 0, stream>>>(z, node_g, node_be, h, N);

    for (int l = 0; l < 3; ++l) {
        const float* eW  = edge_W  + (size_t)l * HD * EDGED;
        const float* eb  = edge_b  + l * HD;
        const float* eg  = edge_g  + l * HD;
        const float* ebe = edge_be + l * HD;

        sl_embed_k<<<1, 64, 0, stream>>>(sl_attr + l * EDGED, eW, eb, eg, ebe, slv);
        pull4_k<<<2048, 256, 0, stream>>>(h, es, rs, eattr, einv + (size_t)l * E, slv,
                                          Wgfh3 + (size_t)l * 4096, Wgfl3 + (size_t)l * 4096,
                                          bg3 + l * HD, ebe, aggr, N);

        mgemm_k<HD, 256, 1, 0><<<mb, 256, 0, stream>>>(
            aggr, W1hi + (size_t)l * 256 * HD, W1lo + (size_t)l * 256 * HD,
            b1 + l * 256, z, N, nullptr);

        hipMemsetAsync(stats, 0, 256 * sizeof(float), stream);
        mgemm_k<256, HD, 0, 1><<<mb, 256, 0, stream>>>(
            z, W2hi + (size_t)l * HD * 256, W2lo + (size_t)l * HD * 256,
            b2 + l * HD, (float*)d_out, N, stats);

        bn_k<<<vblocks, 256, 0, stream>>>((const float*)d_out, stats, bn_g + l * HD, bn_b + l * HD,
                                          (l < 2) ? h : (float*)d_out, total4, 1.f / N, (l < 2) ? 1 : 0);
    }
}

// Round 7
// 1102.823 us; speedup vs baseline: 1.1187x; 1.1187x over previous
//
#include <hip/hip_runtime.h>
#include <cstdint>
#include <cstddef>

#define HD 128
#define EDGED 16
#define NODED 64
#define LN_EPS 1e-5f

typedef __bf16 bf16x8 __attribute__((ext_vector_type(8)));
typedef float  f32x4  __attribute__((ext_vector_type(4)));

__device__ __forceinline__ float gelu_exact(float x) {
    return 0.5f * x * (1.0f + erff(x * 0.7071067811865475f));
}

// fp32 -> bf16 hi/lo split (a ~= hi + lo, lo captures the rounding residual)
__global__ void wconv_k(const float* __restrict__ in, __bf16* __restrict__ hi,
                        __bf16* __restrict__ lo, int n) {
    int i = blockIdx.x * blockDim.x + threadIdx.x;
    if (i < n) {
        float v = in[i];
        __bf16 h = (__bf16)v;
        hi[i] = h;
        lo[i] = (__bf16)(v - (float)h);
    }
}

// ---------------- CSR build ----------------

__global__ void hist_k(const int* __restrict__ ei, int* __restrict__ cnt, int E) {
    int e = blockIdx.x * blockDim.x + threadIdx.x;
    if (e < E) atomicAdd(&cnt[ei[E + e]], 1);
}

__global__ void scan1_k(const int* __restrict__ in, int* __restrict__ out,
                        int* __restrict__ bsum, int n) {
    __shared__ int lds[256];
    int t = threadIdx.x;
    int i = blockIdx.x * 256 + t;
    int v = (i < n) ? in[i] : 0;
    lds[t] = v;
    __syncthreads();
#pragma unroll
    for (int o = 1; o < 256; o <<= 1) {
        int u = (t >= o) ? lds[t - o] : 0;
        __syncthreads();
        lds[t] += u;
        __syncthreads();
    }
    if (i < n) out[i] = lds[t] - v;
    if (t == 255) bsum[blockIdx.x] = lds[255];
}

__global__ void scan2_k(const int* __restrict__ bsum, int* __restrict__ boff, int nb) {
    __shared__ int lds[256];
    int t = threadIdx.x;
    int v = (t < nb) ? bsum[t] : 0;
    lds[t] = v;
    __syncthreads();
#pragma unroll
    for (int o = 1; o < 256; o <<= 1) {
        int u = (t >= o) ? lds[t - o] : 0;
        __syncthreads();
        lds[t] += u;
        __syncthreads();
    }
    if (t < nb) boff[t] = lds[t] - v;
}

// adds block offsets; also emits the scatter cursor copy (saves a d2d memcpy)
__global__ void scan3_k(int* __restrict__ rs, int* __restrict__ cursor,
                        const int* __restrict__ boff, int n, int E) {
    int i = blockIdx.x * 256 + threadIdx.x;
    if (i < n) {
        int v = rs[i] + boff[blockIdx.x];
        rs[i] = v;
        cursor[i] = v;
    }
    if (i == 0) rs[n] = E;
}

__global__ void scatter_k(const int* __restrict__ ei, int* __restrict__ cursor,
                          int2* __restrict__ es, int E) {
    int e = blockIdx.x * blockDim.x + threadIdx.x;
    if (e < E) {
        int dst = ei[E + e];
        int slot = atomicAdd(&cursor[dst], 1);
        es[slot] = make_int2(ei[e], e);
    }
}

// ---------------- edge-LN precompute (+ fused self-loop embed) ----------------
// Per layer l: wm[k]=mean_c W[c][k]; bm=mean(b); Wp=W-wm; bp=b-bm.
// Wg[k][c] = Wp[c][k]*g[c]; bg[c] = bp[c]*g[c]
// M[k][j] = sum_c Wp[c][k]*Wp[c][j]; v[k]=2*sum_c Wp[c][k]*bp[c]; s0=sum bp^2
// => 128*var(attr a) = a^T M a + v.a + s0 (no 128-wide reduce per edge).
// Tail: embeds the learned self-loop attr for this layer into slv3[l].
__global__ void prep_k(const float* __restrict__ edge_W, const float* __restrict__ edge_b,
                       const float* __restrict__ edge_g, const float* __restrict__ edge_be,
                       const float* __restrict__ sl_attr, float* __restrict__ Wg3,
                       float* __restrict__ bg3, float* __restrict__ M3,
                       float* __restrict__ v3, float* __restrict__ s03,
                       float* __restrict__ slv3)
{
    const int l = blockIdx.x;
    const float* W = edge_W + (size_t)l * HD * EDGED;
    const float* b = edge_b + l * HD;
    const float* g = edge_g + l * HD;
    __shared__ float Wp[HD * EDGED];
    __shared__ float bp[HD];
    __shared__ float wm[EDGED];
    __shared__ float Msh[256];
    __shared__ float vsh[EDGED];
    __shared__ float ash[EDGED];
    __shared__ float bmS, s0sh;
    const int t = threadIdx.x;
#pragma unroll
    for (int m = 0; m < 8; ++m) Wp[m * 256 + t] = W[m * 256 + t];
    __syncthreads();
    if (t < EDGED) {
        float s = 0.f;
        for (int c = 0; c < HD; ++c) s += Wp[c * EDGED + t];
        wm[t] = s * (1.f / HD);
    } else if (t == EDGED) {
        float s = 0.f;
        for (int c = 0; c < HD; ++c) s += b[c];
        bmS = s * (1.f / HD);
    }
    __syncthreads();
    if (t < HD) bp[t] = b[t] - bmS;
    __syncthreads();
#pragma unroll
    for (int m = 0; m < 8; ++m) {
        int idx = m * 256 + t;
        int c = idx >> 4, k = idx & 15;
        float val = Wp[idx] - wm[k];
        Wp[idx] = val;
        Wg3[(size_t)l * 2048 + k * HD + c] = val * g[c];
    }
    if (t < HD) bg3[l * HD + t] = bp[t] * g[t];
    __syncthreads();
    {
        int k = t >> 4, j = t & 15;
        float s = 0.f;
        for (int c = 0; c < HD; ++c) s += Wp[c * EDGED + k] * Wp[c * EDGED + j];
        Msh[t] = s;
        M3[l * 256 + t] = s;
    }
    if (t < EDGED) {
        float s = 0.f;
        for (int c = 0; c < HD; ++c) s += Wp[c * EDGED + t] * bp[c];
        vsh[t] = 2.f * s;
        v3[l * EDGED + t] = 2.f * s;
        ash[t] = sl_attr[l * EDGED + t];
    } else if (t == EDGED) {
        float s = 0.f;
        for (int c = 0; c < HD; ++c) s += bp[c] * bp[c];
        s0sh = s;
        s03[l] = s;
    }
    __syncthreads();
    // self-loop embed: out_c = ((Wp.a)*g + bg)*inv + bet, relu
    if (t < HD) {
        float q = s0sh;
#pragma unroll
        for (int k = 0; k < EDGED; ++k) {
            float tk = vsh[k];
#pragma unroll
            for (int j = 0; j < EDGED; ++j) tk = fmaf(Msh[k * 16 + j], ash[j], tk);
            q = fmaf(ash[k], tk, q);
        }
        float inv = rsqrtf(q * (1.f / HD) + LN_EPS);
        float y = 0.f;
#pragma unroll
        for (int k = 0; k < EDGED; ++k) y = fmaf(Wp[t * EDGED + k], ash[k], y);
        slv3[l * HD + t] = fmaxf(fmaf(fmaf(y, g[t], bg3[l * HD + t]), inv, edge_be[l * HD + t]), 0.f);
    }
}

// Per CSR slot: gather attr row once, emit rsqrt(var+eps) for all 3 layers
__launch_bounds__(256)
__global__ void einv_k(const int2* __restrict__ es, const float* __restrict__ eattr,
                       const float* __restrict__ M3, const float* __restrict__ v3,
                       const float* __restrict__ s03, float* __restrict__ einv, int E)
{
    __shared__ float Ms[3 * 256];
    __shared__ float vs[3 * 16];
    __shared__ float s0s[4];
    const int t = threadIdx.x;
    for (int i = t; i < 768; i += 256) Ms[i] = M3[i];
    if (t < 48) vs[t] = v3[t];
    if (t < 3) s0s[t] = s03[t];
    __syncthreads();
    int slot = blockIdx.x * 256 + t;
    if (slot >= E) return;
    int eid = es[slot].y;
    const float4* ap = (const float4*)(eattr + (size_t)eid * EDGED);
    float4 A0 = ap[0], A1 = ap[1], A2 = ap[2], A3 = ap[3];
    float a[16] = {A0.x, A0.y, A0.z, A0.w, A1.x, A1.y, A1.z, A1.w,
                   A2.x, A2.y, A2.z, A2.w, A3.x, A3.y, A3.z, A3.w};
#pragma unroll
    for (int l = 0; l < 3; ++l) {
        float q = s0s[l];
#pragma unroll
        for (int k = 0; k < 16; ++k) {
            const float* Mr = &Ms[l * 256 + k * 16];
            float tk = vs[l * 16 + k];
#pragma unroll
            for (int j = 0; j < 16; ++j) tk = fmaf(Mr[j], a[j], tk);
            q = fmaf(a[k], tk, q);
        }
        einv[(size_t)l * E + slot] = rsqrtf(q * (1.f / HD) + LN_EPS);
    }
}

// ---------------- MFMA GEMM, split-bf16 (bf16x3 ~ fp32 accuracy) ------------
// RG row-groups of 16 per wave; 128-col tile per block (gridDim.y = NC/128).
// acc = hi*hi + hi*lo + lo*hi. RG=2 halves B-load instrs per MFMA for the
// wide GEMM; RG=1 keeps high block count for the narrow ones.
template<int K, int NC, int ACT, int STATS, int RG>
__launch_bounds__(256)
__global__ void mgemm_k(const float* __restrict__ A, const __bf16* __restrict__ Whi,
                        const __bf16* __restrict__ Wlo, const float* __restrict__ bias,
                        float* __restrict__ C, int M, float* __restrict__ stats)
{
    __shared__ float st_lds[2][HD];
    const int t    = threadIdx.x;
    const int lane = t & 63;
    const int wv   = t >> 6;
    const int ln15 = lane & 15;
    const int quad = lane >> 4;
    const int row_base = blockIdx.x * (RG * 64) + wv * (RG * 16);
    const int col0 = blockIdx.y * 128;

    f32x4 acc[RG][8];
#pragma unroll
    for (int g = 0; g < RG; ++g)
#pragma unroll
        for (int nt = 0; nt < 8; ++nt)
#pragma unroll
            for (int r = 0; r < 4; ++r) acc[g][nt][r] = 0.f;

    for (int kc = 0; kc < K; kc += 32) {
        bf16x8 ahi[RG], alo[RG];
#pragma unroll
        for (int g = 0; g < RG; ++g) {
            int row = row_base + g * 16 + ln15;
            float4 a0 = make_float4(0.f, 0.f, 0.f, 0.f), a1 = a0;
            if (row < M) {
                const float* p = A + (size_t)row * K + kc + quad * 8;
                a0 = *(const float4*)p;
                a1 = *(const float4*)(p + 4);
            }
            float av[8] = {a0.x, a0.y, a0.z, a0.w, a1.x, a1.y, a1.z, a1.w};
#pragma unroll
            for (int j = 0; j < 8; ++j) {
                __bf16 hh = (__bf16)av[j];
                ahi[g][j] = hh;
                alo[g][j] = (__bf16)(av[j] - (float)hh);
            }
        }
#pragma unroll
        for (int nt = 0; nt < 8; ++nt) {
            const size_t boff = (size_t)(col0 + nt * 16 + ln15) * K + kc + quad * 8;
            bf16x8 bh = *(const bf16x8*)(Whi + boff);
            bf16x8 bl = *(const bf16x8*)(Wlo + boff);
#pragma unroll
            for (int g = 0; g < RG; ++g) {
                acc[g][nt] = __builtin_amdgcn_mfma_f32_16x16x32_bf16(ahi[g], bh, acc[g][nt], 0, 0, 0);
                acc[g][nt] = __builtin_amdgcn_mfma_f32_16x16x32_bf16(ahi[g], bl, acc[g][nt], 0, 0, 0);
                acc[g][nt] = __builtin_amdgcn_mfma_f32_16x16x32_bf16(alo[g], bh, acc[g][nt], 0, 0, 0);
            }
        }
    }

    if (STATS) {
        if (t < HD) { st_lds[0][t] = 0.f; st_lds[1][t] = 0.f; }
        __syncthreads();
    }

    float bv[8];
#pragma unroll
    for (int nt = 0; nt < 8; ++nt) bv[nt] = bias[col0 + nt * 16 + ln15];

    float s1[8], s2[8];
#pragma unroll
    for (int nt = 0; nt < 8; ++nt) { s1[nt] = 0.f; s2[nt] = 0.f; }

#pragma unroll
    for (int g = 0; g < RG; ++g)
#pragma unroll
        for (int r = 0; r < 4; ++r) {
            int row = row_base + g * 16 + quad * 4 + r;
            if (row < M) {
#pragma unroll
                for (int nt = 0; nt < 8; ++nt) {
                    float v = acc[g][nt][r] + bv[nt];
                    if (ACT == 1) v = gelu_exact(v);
                    C[(size_t)row * NC + col0 + nt * 16 + ln15] = v;
                    if (STATS) { s1[nt] += v; s2[nt] += v * v; }
                }
            }
        }

    if (STATS) {
#pragma unroll
        for (int nt = 0; nt < 8; ++nt) {
            atomicAdd(&st_lds[0][nt * 16 + ln15], s1[nt]);
            atomicAdd(&st_lds[1][nt * 16 + ln15], s2[nt]);
        }
        __syncthreads();
        if (t < HD) {
            atomicAdd(&stats[t],      st_lds[0][t]);
            atomicAdd(&stats[HD + t], st_lds[1][t]);
        }
    }
}

// LayerNorm(+ReLU) over rows of 128, one wave per node
__global__ void ln_relu_k(const float* __restrict__ y, const float* __restrict__ gam,
                          const float* __restrict__ bet, float* __restrict__ h, int N)
{
    int lane = threadIdx.x & 63;
    int c0 = lane * 2;
    float2 g2 = *(const float2*)&gam[c0];
    float2 b2 = *(const float2*)&bet[c0];
    int wid = (blockIdx.x * blockDim.x + threadIdx.x) >> 6;
    int nw  = (gridDim.x * blockDim.x) >> 6;
    for (int n = wid; n < N; n += nw) {
        float2 v = *(const float2*)&y[(size_t)n * HD + c0];
        float s = v.x + v.y;
        float q = v.x * v.x + v.y * v.y;
#pragma unroll
        for (int o = 32; o > 0; o >>= 1) { s += __shfl_xor(s, o, 64); q += __shfl_xor(q, o, 64); }
        float mu  = s * (1.f / 128.f);
        float inv = rsqrtf(q * (1.f / 128.f) - mu * mu + LN_EPS);
        float2 r;
        r.x = fmaxf(fmaf((v.x - mu) * inv, g2.x, b2.x), 0.f);
        r.y = fmaxf(fmaf((v.y - mu) * inv, g2.y, b2.y), 0.f);
        *(float2*)&h[(size_t)n * HD + c0] = r;
    }
}

// ---------------- pull aggregation: grid-stride waves, reg weights ----------
// lane owns channels {lane, lane+64}; edge-embed weights hoisted to VGPRs and
// amortized over ~N/8192 nodes per wave; attr chunk staged in per-wave LDS;
// LN var via precomputed einv. All __shfl at FULL wave exec.
__launch_bounds__(256)
__global__ void pull3_k(const float* __restrict__ h, const int2* __restrict__ es,
                        const int* __restrict__ rs, const float* __restrict__ eattr,
                        const float* __restrict__ einv, const float* __restrict__ slv,
                        const float* __restrict__ Wg, const float* __restrict__ bg,
                        const float* __restrict__ bet, float* __restrict__ aggr, int N)
{
    __shared__ float alds_all[4][64 * EDGED];   // 16 KB: per-wave attr staging
    const int t = threadIdx.x;
    const int lane = t & 63;
    const int wv = t >> 6;
    float* alds = alds_all[wv];

    const int c1 = lane, c2 = lane + 64;
    float w1[16], w2[16];
#pragma unroll
    for (int k = 0; k < 16; ++k) {
        w1[k] = Wg[k * HD + c1];
        w2[k] = Wg[k * HD + c2];
    }
    const float bg1 = bg[c1], bg2 = bg[c2];
    const float bt1 = bet[c1], bt2 = bet[c2];
    const float sl1 = slv[c1], sl2 = slv[c2];

    const int wid = (blockIdx.x * 256 + t) >> 6;
    const int nw  = (gridDim.x * 256) >> 6;

    for (int n = wid; n < N; n += nw) {
        float acc1 = h[(size_t)n * HD + c1] + sl1;
        float acc2 = h[(size_t)n * HD + c2] + sl2;

        const int beg = rs[n], end = rs[n + 1];
        for (int s0 = beg; s0 < end; s0 += 64) {
            int m = end - s0; if (m > 64) m = 64;
            int2 se = make_int2(0, 0);
            float iv = 0.f;
            if (lane < m) { se = es[s0 + lane]; iv = einv[s0 + lane]; }
            // stage attrs: fixed 4 iterations; shfl at full exec (jsrc always a
            // valid lane id 0..63); memory ops predicated on idx < 4m.
#pragma unroll
            for (int it = 0; it < 4; ++it) {
                int idx  = (it << 6) + lane;
                int jsrc = idx >> 2;                       // 0..63
                int eid  = __shfl(se.y, jsrc, 64);         // full-exec shfl
                if (idx < (m << 2)) {
                    float4 av = *(const float4*)&eattr[(size_t)eid * EDGED + ((idx & 3) << 2)];
                    *(float4*)&alds[idx << 2] = av;
                }
            }
            asm volatile("s_waitcnt lgkmcnt(0)" ::: "memory");
            for (int j = 0; j < m; ++j) {
                float4 A0 = *(const float4*)&alds[j * EDGED];
                float4 A1 = *(const float4*)&alds[j * EDGED + 4];
                float4 A2 = *(const float4*)&alds[j * EDGED + 8];
                float4 A3 = *(const float4*)&alds[j * EDGED + 12];
                int   src = __shfl(se.x, j, 64);
                float ivj = __shfl(iv,   j, 64);
                float hv1 = h[(size_t)src * HD + c1];
                float hv2 = h[(size_t)src * HD + c2];
                float a[16] = {A0.x, A0.y, A0.z, A0.w, A1.x, A1.y, A1.z, A1.w,
                               A2.x, A2.y, A2.z, A2.w, A3.x, A3.y, A3.z, A3.w};
                float p1 = bg1, q1 = 0.f, p2 = bg2, q2 = 0.f;
#pragma unroll
                for (int k = 0; k < 16; k += 2) {
                    p1 = fmaf(a[k],     w1[k],     p1);
                    q1 = fmaf(a[k + 1], w1[k + 1], q1);
                    p2 = fmaf(a[k],     w2[k],     p2);
                    q2 = fmaf(a[k + 1], w2[k + 1], q2);
                }
                float v1 = fmaxf(fmaf(p1 + q1, ivj, bt1), 0.f);
                float v2 = fmaxf(fmaf(p2 + q2, ivj, bt2), 0.f);
                acc1 += v1 + hv1;
                acc2 += v2 + hv2;
            }
        }
        aggr[(size_t)n * HD + c1] = acc1;
        aggr[(size_t)n * HD + c2] = acc2;
    }
}

// BatchNorm apply from accumulated column sums; optional ReLU
__global__ void bn_k(const float* __restrict__ hl, const float* __restrict__ stats,
                     const float* __restrict__ gam, const float* __restrict__ bet,
                     float* __restrict__ out, int total4, float invN, int relu)
{
    int idx = blockIdx.x * blockDim.x + threadIdx.x;
    if (idx < total4) {
        int c4 = idx & 31;
        float4 x  = ((const float4*)hl)[idx];
        float4 s1 = ((const float4*)stats)[c4];
        float4 s2 = ((const float4*)stats)[32 + c4];
        float4 g  = ((const float4*)gam)[c4];
        float4 b  = ((const float4*)bet)[c4];
        float4 r;
        {
            float m = s1.x * invN; float v = s2.x * invN - m * m;
            r.x = fmaf((x.x - m) * rsqrtf(v + LN_EPS), g.x, b.x);
        }
        {
            float m = s1.y * invN; float v = s2.y * invN - m * m;
            r.y = fmaf((x.y - m) * rsqrtf(v + LN_EPS), g.y, b.y);
        }
        {
            float m = s1.z * invN; float v = s2.z * invN - m * m;
            r.z = fmaf((x.z - m) * rsqrtf(v + LN_EPS), g.z, b.z);
        }
        {
            float m = s1.w * invN; float v = s2.w * invN - m * m;
            r.w = fmaf((x.w - m) * rsqrtf(v + LN_EPS), g.w, b.w);
        }
        if (relu) {
            r.x = fmaxf(r.x, 0.f); r.y = fmaxf(r.y, 0.f);
            r.z = fmaxf(r.z, 0.f); r.w = fmaxf(r.w, 0.f);
        }
        ((float4*)out)[idx] = r;
    }
}

extern "C" void kernel_launch(void* const* d_in, const int* in_sizes, int n_in,
                              void* d_out, int out_size, void* d_ws, size_t ws_size,
                              hipStream_t stream)
{
    const float* x       = (const float*)d_in[0];
    const int*   ei      = (const int*)d_in[1];
    const float* eattr   = (const float*)d_in[2];
    const float* node_W  = (const float*)d_in[3];
    const float* node_b  = (const float*)d_in[4];
    const float* node_g  = (const float*)d_in[5];
    const float* node_be = (const float*)d_in[6];
    const float* edge_W  = (const float*)d_in[7];
    const float* edge_b  = (const float*)d_in[8];
    const float* edge_g  = (const float*)d_in[9];
    const float* edge_be = (const float*)d_in[10];
    const float* sl_attr = (const float*)d_in[11];
    const float* W1      = (const float*)d_in[12];
    const float* b1      = (const float*)d_in[13];
    const float* W2      = (const float*)d_in[14];
    const float* b2      = (const float*)d_in[15];
    const float* bn_g    = (const float*)d_in[16];
    const float* bn_b    = (const float*)d_in[17];

    const int N = in_sizes[0] / NODED;
    const int E = in_sizes[1] / 2;

    // explicit 16B-aligned workspace layout
    char* base = (char*)d_ws;
    size_t off = 0;
    auto take = [&](size_t nbytes) -> void* {
        void* p = base + off;
        off = (off + nbytes + 15) & ~(size_t)15;
        return p;
    };
    float* h      = (float*)take((size_t)N * HD * 4);
    float* aggr   = (float*)take((size_t)N * HD * 4);
    float* z      = (float*)take((size_t)N * 256 * 4);
    float* slv3   = (float*)take(3 * HD * 4);
    float* stats  = (float*)take(3 * 256 * 4);
    int*   cnt    = (int*)take((size_t)N * 4);
    int*   cursor = (int*)take((size_t)N * 4);
    int*   bsum   = (int*)take(256 * 4);
    int*   boff   = (int*)take(256 * 4);
    int*   rs     = (int*)take(((size_t)N + 2) * 4);
    int2*  es     = (int2*)take((size_t)E * 8);
    float* einv   = (float*)take((size_t)3 * E * 4);
    float* Wg3    = (float*)take(3 * 2048 * 4);
    float* bg3    = (float*)take(3 * HD * 4);
    float* M3     = (float*)take(3 * 256 * 4);
    float* v3     = (float*)take(3 * 16 * 4);
    float* s03    = (float*)take(4 * 4);
    __bf16* nWhi  = (__bf16*)take((size_t)HD * NODED * 2);
    __bf16* nWlo  = (__bf16*)take((size_t)HD * NODED * 2);
    __bf16* W1hi  = (__bf16*)take((size_t)3 * 256 * HD * 2);
    __bf16* W1lo  = (__bf16*)take((size_t)3 * 256 * HD * 2);
    __bf16* W2hi  = (__bf16*)take((size_t)3 * HD * 256 * 2);
    __bf16* W2lo  = (__bf16*)take((size_t)3 * HD * 256 * 2);

    // weight split-bf16 conversion (layouts already [N][K] row-major)
    wconv_k<<<(HD * NODED + 255) / 256, 256, 0, stream>>>(node_W, nWhi, nWlo, HD * NODED);
    wconv_k<<<(3 * 256 * HD + 255) / 256, 256, 0, stream>>>(W1, W1hi, W1lo, 3 * 256 * HD);
    wconv_k<<<(3 * 256 * HD + 255) / 256, 256, 0, stream>>>(W2, W2hi, W2lo, 3 * 256 * HD);

    // edge-LN precompute + self-loop embed (all 3 layers)
    prep_k<<<3, 256, 0, stream>>>(edge_W, edge_b, edge_g, edge_be, sl_attr,
                                  Wg3, bg3, M3, v3, s03, slv3);

    // ---- CSR build ----
    const int eblocks = (E + 255) / 256;
    const int nblocks = (N + 255) / 256;
    hipMemsetAsync(cnt, 0, (size_t)N * sizeof(int), stream);
    hist_k<<<eblocks, 256, 0, stream>>>(ei, cnt, E);
    scan1_k<<<nblocks, 256, 0, stream>>>(cnt, rs, bsum, N);
    scan2_k<<<1, 256, 0, stream>>>(bsum, boff, nblocks);
    scan3_k<<<nblocks, 256, 0, stream>>>(rs, cursor, boff, N, E);
    scatter_k<<<eblocks, 256, 0, stream>>>(ei, cursor, es, E);

    // per-slot inv-std for all 3 layers (one attr gather)
    einv_k<<<eblocks, 256, 0, stream>>>(es, eattr, M3, v3, s03, einv, E);

    const int total4  = N * (HD / 4);
    const int vblocks = (total4 + 255) / 256;

    // node embed: Linear (MFMA) -> LN -> ReLU
    mgemm_k<NODED, HD, 0, 0, 1><<<dim3((N + 63) / 64, 1), 256, 0, stream>>>(
        x, nWhi, nWlo, node_b, z, N, nullptr);
    ln_relu_k<<<(N + 3) / 4, 256, 0, stream>>>(z, node_g, node_be, h, N);

    hipMemsetAsync(stats, 0, 3 * 256 * sizeof(float), stream);

    for (int l = 0; l < 3; ++l) {
        pull3_k<<<2048, 256, 0, stream>>>(h, es, rs, eattr, einv + (size_t)l * E,
                                          slv3 + l * HD, Wg3 + (size_t)l * 2048,
                                          bg3 + l * HD, edge_be + l * HD, aggr, N);

        mgemm_k<HD, 256, 1, 0, 2><<<dim3((N + 127) / 128, 2), 256, 0, stream>>>(
            aggr, W1hi + (size_t)l * 256 * HD, W1lo + (size_t)l * 256 * HD,
            b1 + l * 256, z, N, nullptr);

        mgemm_k<256, HD, 0, 1, 1><<<dim3((N + 63) / 64, 1), 256, 0, stream>>>(
            z, W2hi + (size_t)l * HD * 256, W2lo + (size_t)l * HD * 256,
            b2 + l * HD, (float*)d_out, N, stats + l * 256);

        bn_k<<<vblocks, 256, 0, stream>>>((const float*)d_out, stats + l * 256,
                                          bn_g + l * HD, bn_b + l * HD,
                                          (l < 2) ? h : (float*)d_out, total4, 1.f / N, (l < 2) ? 1 : 0);
    }
}

// Round 8
// 1004.316 us; speedup vs baseline: 1.2285x; 1.0981x over previous
//
#include <hip/hip_runtime.h>
#include <cstdint>
#include <cstddef>

#define HD 128
#define EDGED 16
#define NODED 64
#define LN_EPS 1e-5f

typedef __bf16 bf16x8 __attribute__((ext_vector_type(8)));
typedef float  f32x4  __attribute__((ext_vector_type(4)));

__device__ __forceinline__ float gelu_exact(float x) {
    return 0.5f * x * (1.0f + erff(x * 0.7071067811865475f));
}

// fp32 -> bf16 hi/lo split (a ~= hi + lo, lo captures the rounding residual)
__global__ void wconv_k(const float* __restrict__ in, __bf16* __restrict__ hi,
                        __bf16* __restrict__ lo, int n) {
    int i = blockIdx.x * blockDim.x + threadIdx.x;
    if (i < n) {
        float v = in[i];
        __bf16 h = (__bf16)v;
        hi[i] = h;
        lo[i] = (__bf16)(v - (float)h);
    }
}

// ---------------- CSR build ----------------

__global__ void hist_k(const int* __restrict__ ei, int* __restrict__ cnt, int E) {
    int e = blockIdx.x * blockDim.x + threadIdx.x;
    if (e < E) atomicAdd(&cnt[ei[E + e]], 1);
}

__global__ void scan1_k(const int* __restrict__ in, int* __restrict__ out,
                        int* __restrict__ bsum, int n) {
    __shared__ int lds[256];
    int t = threadIdx.x;
    int i = blockIdx.x * 256 + t;
    int v = (i < n) ? in[i] : 0;
    lds[t] = v;
    __syncthreads();
#pragma unroll
    for (int o = 1; o < 256; o <<= 1) {
        int u = (t >= o) ? lds[t - o] : 0;
        __syncthreads();
        lds[t] += u;
        __syncthreads();
    }
    if (i < n) out[i] = lds[t] - v;
    if (t == 255) bsum[blockIdx.x] = lds[255];
}

__global__ void scan2_k(const int* __restrict__ bsum, int* __restrict__ boff, int nb) {
    __shared__ int lds[256];
    int t = threadIdx.x;
    int v = (t < nb) ? bsum[t] : 0;
    lds[t] = v;
    __syncthreads();
#pragma unroll
    for (int o = 1; o < 256; o <<= 1) {
        int u = (t >= o) ? lds[t - o] : 0;
        __syncthreads();
        lds[t] += u;
        __syncthreads();
    }
    if (t < nb) boff[t] = lds[t] - v;
}

// adds block offsets; also emits the scatter cursor copy (saves a d2d memcpy)
__global__ void scan3_k(int* __restrict__ rs, int* __restrict__ cursor,
                        const int* __restrict__ boff, int n, int E) {
    int i = blockIdx.x * 256 + threadIdx.x;
    if (i < n) {
        int v = rs[i] + boff[blockIdx.x];
        rs[i] = v;
        cursor[i] = v;
    }
    if (i == 0) rs[n] = E;
}

__global__ void scatter_k(const int* __restrict__ ei, int* __restrict__ cursor,
                          int2* __restrict__ es, int E) {
    int e = blockIdx.x * blockDim.x + threadIdx.x;
    if (e < E) {
        int dst = ei[E + e];
        int slot = atomicAdd(&cursor[dst], 1);
        es[slot] = make_int2(ei[e], e);
    }
}

// ---------------- edge-LN precompute (+ fused self-loop embed) ----------------
// Per layer l: wm[k]=mean_c W[c][k]; bm=mean(b); Wp=W-wm; bp=b-bm.
// Wg[k][c] = Wp[c][k]*g[c]; bg[c] = bp[c]*g[c]
// M[k][j] = sum_c Wp[c][k]*Wp[c][j]; v[k]=2*sum_c Wp[c][k]*bp[c]; s0=sum bp^2
// => 128*var(attr a) = a^T M a + v.a + s0 (no 128-wide reduce per edge).
// Tail: embeds the learned self-loop attr for this layer into slv3[l].
__global__ void prep_k(const float* __restrict__ edge_W, const float* __restrict__ edge_b,
                       const float* __restrict__ edge_g, const float* __restrict__ edge_be,
                       const float* __restrict__ sl_attr, float* __restrict__ Wg3,
                       float* __restrict__ bg3, float* __restrict__ M3,
                       float* __restrict__ v3, float* __restrict__ s03,
                       float* __restrict__ slv3)
{
    const int l = blockIdx.x;
    const float* W = edge_W + (size_t)l * HD * EDGED;
    const float* b = edge_b + l * HD;
    const float* g = edge_g + l * HD;
    __shared__ float Wp[HD * EDGED];
    __shared__ float bp[HD];
    __shared__ float wm[EDGED];
    __shared__ float Msh[256];
    __shared__ float vsh[EDGED];
    __shared__ float ash[EDGED];
    __shared__ float bmS, s0sh;
    const int t = threadIdx.x;
#pragma unroll
    for (int m = 0; m < 8; ++m) Wp[m * 256 + t] = W[m * 256 + t];
    __syncthreads();
    if (t < EDGED) {
        float s = 0.f;
        for (int c = 0; c < HD; ++c) s += Wp[c * EDGED + t];
        wm[t] = s * (1.f / HD);
    } else if (t == EDGED) {
        float s = 0.f;
        for (int c = 0; c < HD; ++c) s += b[c];
        bmS = s * (1.f / HD);
    }
    __syncthreads();
    if (t < HD) bp[t] = b[t] - bmS;
    __syncthreads();
#pragma unroll
    for (int m = 0; m < 8; ++m) {
        int idx = m * 256 + t;
        int c = idx >> 4, k = idx & 15;
        float val = Wp[idx] - wm[k];
        Wp[idx] = val;
        Wg3[(size_t)l * 2048 + k * HD + c] = val * g[c];
    }
    if (t < HD) bg3[l * HD + t] = bp[t] * g[t];
    __syncthreads();
    {
        int k = t >> 4, j = t & 15;
        float s = 0.f;
        for (int c = 0; c < HD; ++c) s += Wp[c * EDGED + k] * Wp[c * EDGED + j];
        Msh[t] = s;
        M3[l * 256 + t] = s;
    }
    if (t < EDGED) {
        float s = 0.f;
        for (int c = 0; c < HD; ++c) s += Wp[c * EDGED + t] * bp[c];
        vsh[t] = 2.f * s;
        v3[l * EDGED + t] = 2.f * s;
        ash[t] = sl_attr[l * EDGED + t];
    } else if (t == EDGED) {
        float s = 0.f;
        for (int c = 0; c < HD; ++c) s += bp[c] * bp[c];
        s0sh = s;
        s03[l] = s;
    }
    __syncthreads();
    // self-loop embed: out_c = ((Wp.a)*g + bg)*inv + bet, relu
    if (t < HD) {
        float q = s0sh;
#pragma unroll
        for (int k = 0; k < EDGED; ++k) {
            float tk = vsh[k];
#pragma unroll
            for (int j = 0; j < EDGED; ++j) tk = fmaf(Msh[k * 16 + j], ash[j], tk);
            q = fmaf(ash[k], tk, q);
        }
        float inv = rsqrtf(q * (1.f / HD) + LN_EPS);
        float y = 0.f;
#pragma unroll
        for (int k = 0; k < EDGED; ++k) y = fmaf(Wp[t * EDGED + k], ash[k], y);
        slv3[l * HD + t] = fmaxf(fmaf(fmaf(y, g[t], bg3[l * HD + t]), inv, edge_be[l * HD + t]), 0.f);
    }
}

// Per CSR slot: gather attr row once, emit rsqrt(var+eps) for all 3 layers
__launch_bounds__(256)
__global__ void einv_k(const int2* __restrict__ es, const float* __restrict__ eattr,
                       const float* __restrict__ M3, const float* __restrict__ v3,
                       const float* __restrict__ s03, float* __restrict__ einv, int E)
{
    __shared__ float Ms[3 * 256];
    __shared__ float vs[3 * 16];
    __shared__ float s0s[4];
    const int t = threadIdx.x;
    for (int i = t; i < 768; i += 256) Ms[i] = M3[i];
    if (t < 48) vs[t] = v3[t];
    if (t < 3) s0s[t] = s03[t];
    __syncthreads();
    int slot = blockIdx.x * 256 + t;
    if (slot >= E) return;
    int eid = es[slot].y;
    const float4* ap = (const float4*)(eattr + (size_t)eid * EDGED);
    float4 A0 = ap[0], A1 = ap[1], A2 = ap[2], A3 = ap[3];
    float a[16] = {A0.x, A0.y, A0.z, A0.w, A1.x, A1.y, A1.z, A1.w,
                   A2.x, A2.y, A2.z, A2.w, A3.x, A3.y, A3.z, A3.w};
#pragma unroll
    for (int l = 0; l < 3; ++l) {
        float q = s0s[l];
#pragma unroll
        for (int k = 0; k < 16; ++k) {
            const float* Mr = &Ms[l * 256 + k * 16];
            float tk = vs[l * 16 + k];
#pragma unroll
            for (int j = 0; j < 16; ++j) tk = fmaf(Mr[j], a[j], tk);
            q = fmaf(a[k], tk, q);
        }
        einv[(size_t)l * E + slot] = rsqrtf(q * (1.f / HD) + LN_EPS);
    }
}

// ---------------- MFMA GEMM v2: bf16 hi/lo inputs, reg double-buffer --------
// A pre-split to bf16 hi/lo [M][K]; W pre-split [NC][K]. Wave: 32 rows x 64
// cols (RG=2, NT=4); block 128 rows; gridDim.y = NC/64 col tiles. K-loop
// prefetches step s+1's A/B frags before MFMAing step s (latency hiding).
// acc = hi*hi + hi*lo + lo*hi (~fp32 accuracy). Output fp32 or bf16 hi/lo.
template<int K, int NC, int ACT, int STATS, int OUTBF>
__launch_bounds__(256)
__global__ void mgemm_k(const __bf16* __restrict__ Ahi, const __bf16* __restrict__ Alo,
                        const __bf16* __restrict__ Whi, const __bf16* __restrict__ Wlo,
                        const float* __restrict__ bias, float* __restrict__ C,
                        __bf16* __restrict__ Chi, __bf16* __restrict__ Clo,
                        int M, float* __restrict__ stats)
{
    constexpr int RG = 2;
    constexpr int NT = 4;
    constexpr int NK = K / 32;
    __shared__ float st_lds[2][64];

    const int t    = threadIdx.x;
    const int lane = t & 63;
    const int wv   = t >> 6;
    const int ln15 = lane & 15;
    const int quad = lane >> 4;
    const int row_base = blockIdx.x * 128 + wv * 32;
    const int col0 = blockIdx.y * 64;

    f32x4 acc[RG][NT];
#pragma unroll
    for (int g = 0; g < RG; ++g)
#pragma unroll
        for (int nt = 0; nt < NT; ++nt)
#pragma unroll
            for (int r = 0; r < 4; ++r) acc[g][nt][r] = 0.f;

    size_t arow[RG];
#pragma unroll
    for (int g = 0; g < RG; ++g) {
        int row = row_base + g * 16 + ln15;
        row = row < M ? row : M - 1;          // clamp: junk values, store masked
        arow[g] = (size_t)row * K + quad * 8;
    }
    size_t brow[NT];
#pragma unroll
    for (int nt = 0; nt < NT; ++nt)
        brow[nt] = (size_t)(col0 + nt * 16 + ln15) * K + quad * 8;

    bf16x8 a0h[RG], a0l[RG], a1h[RG], a1l[RG];
    bf16x8 b0h[NT], b0l[NT], b1h[NT], b1l[NT];

#define LD_A(kc, AH, AL) { \
    _Pragma("unroll") \
    for (int g = 0; g < RG; ++g) { \
        AH[g] = *(const bf16x8*)(Ahi + arow[g] + (kc)); \
        AL[g] = *(const bf16x8*)(Alo + arow[g] + (kc)); \
    } }
#define LD_B(kc, BH, BL) { \
    _Pragma("unroll") \
    for (int nt = 0; nt < NT; ++nt) { \
        BH[nt] = *(const bf16x8*)(Whi + brow[nt] + (kc)); \
        BL[nt] = *(const bf16x8*)(Wlo + brow[nt] + (kc)); \
    } }
#define DO_MFMA(AH, AL, BH, BL) { \
    _Pragma("unroll") \
    for (int nt = 0; nt < NT; ++nt) { \
        _Pragma("unroll") \
        for (int g = 0; g < RG; ++g) { \
            acc[g][nt] = __builtin_amdgcn_mfma_f32_16x16x32_bf16(AH[g], BH[nt], acc[g][nt], 0, 0, 0); \
            acc[g][nt] = __builtin_amdgcn_mfma_f32_16x16x32_bf16(AH[g], BL[nt], acc[g][nt], 0, 0, 0); \
            acc[g][nt] = __builtin_amdgcn_mfma_f32_16x16x32_bf16(AL[g], BH[nt], acc[g][nt], 0, 0, 0); \
        } } }

    LD_A(0, a0h, a0l);
    LD_B(0, b0h, b0l);
    for (int s = 0; s < NK; s += 2) {
        LD_A((s + 1) * 32, a1h, a1l);
        LD_B((s + 1) * 32, b1h, b1l);
        DO_MFMA(a0h, a0l, b0h, b0l);
        if (s + 2 < NK) {
            LD_A((s + 2) * 32, a0h, a0l);
            LD_B((s + 2) * 32, b0h, b0l);
        }
        DO_MFMA(a1h, a1l, b1h, b1l);
    }
#undef LD_A
#undef LD_B
#undef DO_MFMA

    if (STATS) {
        if (t < 64) { st_lds[0][t] = 0.f; st_lds[1][t] = 0.f; }
        __syncthreads();
    }

    float bv[NT];
#pragma unroll
    for (int nt = 0; nt < NT; ++nt) bv[nt] = bias[col0 + nt * 16 + ln15];

    float s1[NT], s2[NT];
#pragma unroll
    for (int nt = 0; nt < NT; ++nt) { s1[nt] = 0.f; s2[nt] = 0.f; }

#pragma unroll
    for (int g = 0; g < RG; ++g)
#pragma unroll
        for (int r = 0; r < 4; ++r) {
            int row = row_base + g * 16 + quad * 4 + r;
            if (row < M) {
#pragma unroll
                for (int nt = 0; nt < NT; ++nt) {
                    float v = acc[g][nt][r] + bv[nt];
                    if (ACT == 1) v = gelu_exact(v);
                    size_t ci = (size_t)row * NC + col0 + nt * 16 + ln15;
                    if (OUTBF) {
                        __bf16 hh = (__bf16)v;
                        Chi[ci] = hh;
                        Clo[ci] = (__bf16)(v - (float)hh);
                    } else {
                        C[ci] = v;
                    }
                    if (STATS) { s1[nt] += v; s2[nt] += v * v; }
                }
            }
        }

    if (STATS) {
#pragma unroll
        for (int nt = 0; nt < NT; ++nt) {
            atomicAdd(&st_lds[0][nt * 16 + ln15], s1[nt]);
            atomicAdd(&st_lds[1][nt * 16 + ln15], s2[nt]);
        }
        __syncthreads();
        if (t < 64) {
            atomicAdd(&stats[col0 + t],      st_lds[0][t]);
            atomicAdd(&stats[HD + col0 + t], st_lds[1][t]);
        }
    }
}

// LayerNorm(+ReLU) over rows of 128, one wave per node
__global__ void ln_relu_k(const float* __restrict__ y, const float* __restrict__ gam,
                          const float* __restrict__ bet, float* __restrict__ h, int N)
{
    int lane = threadIdx.x & 63;
    int c0 = lane * 2;
    float2 g2 = *(const float2*)&gam[c0];
    float2 b2 = *(const float2*)&bet[c0];
    int wid = (blockIdx.x * blockDim.x + threadIdx.x) >> 6;
    int nw  = (gridDim.x * blockDim.x) >> 6;
    for (int n = wid; n < N; n += nw) {
        float2 v = *(const float2*)&y[(size_t)n * HD + c0];
        float s = v.x + v.y;
        float q = v.x * v.x + v.y * v.y;
#pragma unroll
        for (int o = 32; o > 0; o >>= 1) { s += __shfl_xor(s, o, 64); q += __shfl_xor(q, o, 64); }
        float mu  = s * (1.f / 128.f);
        float inv = rsqrtf(q * (1.f / 128.f) - mu * mu + LN_EPS);
        float2 r;
        r.x = fmaxf(fmaf((v.x - mu) * inv, g2.x, b2.x), 0.f);
        r.y = fmaxf(fmaf((v.y - mu) * inv, g2.y, b2.y), 0.f);
        *(float2*)&h[(size_t)n * HD + c0] = r;
    }
}

// ---------------- pull aggregation: one wave per node, reg weights ----------
// lane owns channels {lane, lane+64}; edge-embed weights in VGPRs; attr chunk
// staged in per-wave LDS; LN var via precomputed einv. Writes aggr as bf16
// hi/lo (mlp1's MFMA input). All __shfl at FULL wave exec.
__launch_bounds__(256)
__global__ void pull3_k(const float* __restrict__ h, const int2* __restrict__ es,
                        const int* __restrict__ rs, const float* __restrict__ eattr,
                        const float* __restrict__ einv, const float* __restrict__ slv,
                        const float* __restrict__ Wg, const float* __restrict__ bg,
                        const float* __restrict__ bet, __bf16* __restrict__ Ahi,
                        __bf16* __restrict__ Alo, int N)
{
    __shared__ float alds_all[4][64 * EDGED];   // 16 KB: per-wave attr staging
    const int t = threadIdx.x;
    const int lane = t & 63;
    const int wv = t >> 6;
    float* alds = alds_all[wv];

    const int c1 = lane, c2 = lane + 64;
    float w1[16], w2[16];
#pragma unroll
    for (int k = 0; k < 16; ++k) {
        w1[k] = Wg[k * HD + c1];
        w2[k] = Wg[k * HD + c2];
    }
    const float bg1 = bg[c1], bg2 = bg[c2];
    const float bt1 = bet[c1], bt2 = bet[c2];

    const int n = (blockIdx.x << 2) + wv;
    if (n >= N) return;

    float acc1 = h[(size_t)n * HD + c1] + slv[c1];
    float acc2 = h[(size_t)n * HD + c2] + slv[c2];

    const int beg = rs[n], end = rs[n + 1];
    for (int s0 = beg; s0 < end; s0 += 64) {
        int m = end - s0; if (m > 64) m = 64;
        int2 se = make_int2(0, 0);
        float iv = 0.f;
        if (lane < m) { se = es[s0 + lane]; iv = einv[s0 + lane]; }
        // stage attrs: fixed 4 iterations; shfl at full exec (jsrc always a
        // valid lane id 0..63); memory ops predicated on idx < 4m.
#pragma unroll
        for (int it = 0; it < 4; ++it) {
            int idx  = (it << 6) + lane;
            int jsrc = idx >> 2;                       // 0..63
            int eid  = __shfl(se.y, jsrc, 64);         // full-exec shfl
            if (idx < (m << 2)) {
                float4 av = *(const float4*)&eattr[(size_t)eid * EDGED + ((idx & 3) << 2)];
                *(float4*)&alds[idx << 2] = av;
            }
        }
        asm volatile("s_waitcnt lgkmcnt(0)" ::: "memory");
        for (int j = 0; j < m; ++j) {
            float4 A0 = *(const float4*)&alds[j * EDGED];
            float4 A1 = *(const float4*)&alds[j * EDGED + 4];
            float4 A2 = *(const float4*)&alds[j * EDGED + 8];
            float4 A3 = *(const float4*)&alds[j * EDGED + 12];
            int   src = __shfl(se.x, j, 64);
            float ivj = __shfl(iv,   j, 64);
            float hv1 = h[(size_t)src * HD + c1];
            float hv2 = h[(size_t)src * HD + c2];
            float a[16] = {A0.x, A0.y, A0.z, A0.w, A1.x, A1.y, A1.z, A1.w,
                           A2.x, A2.y, A2.z, A2.w, A3.x, A3.y, A3.z, A3.w};
            float p1 = bg1, q1 = 0.f, p2 = bg2, q2 = 0.f;
#pragma unroll
            for (int k = 0; k < 16; k += 2) {
                p1 = fmaf(a[k],     w1[k],     p1);
                q1 = fmaf(a[k + 1], w1[k + 1], q1);
                p2 = fmaf(a[k],     w2[k],     p2);
                q2 = fmaf(a[k + 1], w2[k + 1], q2);
            }
            float v1 = fmaxf(fmaf(p1 + q1, ivj, bt1), 0.f);
            float v2 = fmaxf(fmaf(p2 + q2, ivj, bt2), 0.f);
            acc1 += v1 + hv1;
            acc2 += v2 + hv2;
        }
    }
    __bf16 h1 = (__bf16)acc1, h2 = (__bf16)acc2;
    Ahi[(size_t)n * HD + c1] = h1;
    Alo[(size_t)n * HD + c1] = (__bf16)(acc1 - (float)h1);
    Ahi[(size_t)n * HD + c2] = h2;
    Alo[(size_t)n * HD + c2] = (__bf16)(acc2 - (float)h2);
}

// BatchNorm apply from accumulated column sums; optional ReLU
__global__ void bn_k(const float* __restrict__ hl, const float* __restrict__ stats,
                     const float* __restrict__ gam, const float* __restrict__ bet,
                     float* __restrict__ out, int total4, float invN, int relu)
{
    int idx = blockIdx.x * blockDim.x + threadIdx.x;
    if (idx < total4) {
        int c4 = idx & 31;
        float4 x  = ((const float4*)hl)[idx];
        float4 s1 = ((const float4*)stats)[c4];
        float4 s2 = ((const float4*)stats)[32 + c4];
        float4 g  = ((const float4*)gam)[c4];
        float4 b  = ((const float4*)bet)[c4];
        float4 r;
        {
            float m = s1.x * invN; float v = s2.x * invN - m * m;
            r.x = fmaf((x.x - m) * rsqrtf(v + LN_EPS), g.x, b.x);
        }
        {
            float m = s1.y * invN; float v = s2.y * invN - m * m;
            r.y = fmaf((x.y - m) * rsqrtf(v + LN_EPS), g.y, b.y);
        }
        {
            float m = s1.z * invN; float v = s2.z * invN - m * m;
            r.z = fmaf((x.z - m) * rsqrtf(v + LN_EPS), g.z, b.z);
        }
        {
            float m = s1.w * invN; float v = s2.w * invN - m * m;
            r.w = fmaf((x.w - m) * rsqrtf(v + LN_EPS), g.w, b.w);
        }
        if (relu) {
            r.x = fmaxf(r.x, 0.f); r.y = fmaxf(r.y, 0.f);
            r.z = fmaxf(r.z, 0.f); r.w = fmaxf(r.w, 0.f);
        }
        ((float4*)out)[idx] = r;
    }
}

extern "C" void kernel_launch(void* const* d_in, const int* in_sizes, int n_in,
                              void* d_out, int out_size, void* d_ws, size_t ws_size,
                              hipStream_t stream)
{
    const float* x       = (const float*)d_in[0];
    const int*   ei      = (const int*)d_in[1];
    const float* eattr   = (const float*)d_in[2];
    const float* node_W  = (const float*)d_in[3];
    const float* node_b  = (const float*)d_in[4];
    const float* node_g  = (const float*)d_in[5];
    const float* node_be = (const float*)d_in[6];
    const float* edge_W  = (const float*)d_in[7];
    const float* edge_b  = (const float*)d_in[8];
    const float* edge_g  = (const float*)d_in[9];
    const float* edge_be = (const float*)d_in[10];
    const float* sl_attr = (const float*)d_in[11];
    const float* W1      = (const float*)d_in[12];
    const float* b1      = (const float*)d_in[13];
    const float* W2      = (const float*)d_in[14];
    const float* b2      = (const float*)d_in[15];
    const float* bn_g    = (const float*)d_in[16];
    const float* bn_b    = (const float*)d_in[17];

    const int N = in_sizes[0] / NODED;
    const int E = in_sizes[1] / 2;

    // explicit 16B-aligned workspace layout
    char* base = (char*)d_ws;
    size_t off = 0;
    auto take = [&](size_t nbytes) -> void* {
        void* p = base + off;
        off = (off + nbytes + 15) & ~(size_t)15;
        return p;
    };
    float*  h      = (float*)take((size_t)N * HD * 4);
    float*  z      = (float*)take((size_t)N * HD * 4);     // node-embed pre-LN (fp32)
    __bf16* aghi   = (__bf16*)take((size_t)N * HD * 2);    // aggr bf16 hi
    __bf16* aglo   = (__bf16*)take((size_t)N * HD * 2);
    __bf16* zhi    = (__bf16*)take((size_t)N * 256 * 2);   // mlp1 out bf16 hi
    __bf16* zlo    = (__bf16*)take((size_t)N * 256 * 2);
    __bf16* xhi    = (__bf16*)take((size_t)N * NODED * 2);
    __bf16* xlo    = (__bf16*)take((size_t)N * NODED * 2);
    float*  slv3   = (float*)take(3 * HD * 4);
    float*  stats  = (float*)take(3 * 256 * 4);
    int*    cnt    = (int*)take((size_t)N * 4);
    int*    cursor = (int*)take((size_t)N * 4);
    int*    bsum   = (int*)take(256 * 4);
    int*    boff   = (int*)take(256 * 4);
    int*    rs     = (int*)take(((size_t)N + 2) * 4);
    int2*   es     = (int2*)take((size_t)E * 8);
    float*  einv   = (float*)take((size_t)3 * E * 4);
    float*  Wg3    = (float*)take(3 * 2048 * 4);
    float*  bg3    = (float*)take(3 * HD * 4);
    float*  M3     = (float*)take(3 * 256 * 4);
    float*  v3     = (float*)take(3 * 16 * 4);
    float*  s03    = (float*)take(4 * 4);
    __bf16* nWhi   = (__bf16*)take((size_t)HD * NODED * 2);
    __bf16* nWlo   = (__bf16*)take((size_t)HD * NODED * 2);
    __bf16* W1hi   = (__bf16*)take((size_t)3 * 256 * HD * 2);
    __bf16* W1lo   = (__bf16*)take((size_t)3 * 256 * HD * 2);
    __bf16* W2hi   = (__bf16*)take((size_t)3 * HD * 256 * 2);
    __bf16* W2lo   = (__bf16*)take((size_t)3 * HD * 256 * 2);

    // bf16 hi/lo splits: weights ([N][K] row-major already) and x
    wconv_k<<<(HD * NODED + 255) / 256, 256, 0, stream>>>(node_W, nWhi, nWlo, HD * NODED);
    wconv_k<<<(3 * 256 * HD + 255) / 256, 256, 0, stream>>>(W1, W1hi, W1lo, 3 * 256 * HD);
    wconv_k<<<(3 * 256 * HD + 255) / 256, 256, 0, stream>>>(W2, W2hi, W2lo, 3 * 256 * HD);
    wconv_k<<<((int)((size_t)N * NODED + 255) / 256), 256, 0, stream>>>(x, xhi, xlo, N * NODED);

    // edge-LN precompute + self-loop embed (all 3 layers)
    prep_k<<<3, 256, 0, stream>>>(edge_W, edge_b, edge_g, edge_be, sl_attr,
                                  Wg3, bg3, M3, v3, s03, slv3);

    // ---- CSR build ----
    const int eblocks = (E + 255) / 256;
    const int nblocks = (N + 255) / 256;
    hipMemsetAsync(cnt, 0, (size_t)N * sizeof(int), stream);
    hist_k<<<eblocks, 256, 0, stream>>>(ei, cnt, E);
    scan1_k<<<nblocks, 256, 0, stream>>>(cnt, rs, bsum, N);
    scan2_k<<<1, 256, 0, stream>>>(bsum, boff, nblocks);
    scan3_k<<<nblocks, 256, 0, stream>>>(rs, cursor, boff, N, E);
    scatter_k<<<eblocks, 256, 0, stream>>>(ei, cursor, es, E);

    // per-slot inv-std for all 3 layers (one attr gather)
    einv_k<<<eblocks, 256, 0, stream>>>(es, eattr, M3, v3, s03, einv, E);

    const int total4  = N * (HD / 4);
    const int vblocks = (total4 + 255) / 256;
    const int pblocks = (N + 3) / 4;
    const int gb128   = (N + 127) / 128;

    // node embed: Linear (MFMA) -> LN -> ReLU
    mgemm_k<NODED, HD, 0, 0, 0><<<dim3(gb128, 2), 256, 0, stream>>>(
        xhi, xlo, nWhi, nWlo, node_b, z, nullptr, nullptr, N, nullptr);
    ln_relu_k<<<pblocks, 256, 0, stream>>>(z, node_g, node_be, h, N);

    hipMemsetAsync(stats, 0, 3 * 256 * sizeof(float), stream);

    for (int l = 0; l < 3; ++l) {
        pull3_k<<<pblocks, 256, 0, stream>>>(h, es, rs, eattr, einv + (size_t)l * E,
                                             slv3 + l * HD, Wg3 + (size_t)l * 2048,
                                             bg3 + l * HD, edge_be + l * HD,
                                             aghi, aglo, N);

        mgemm_k<HD, 256, 1, 0, 1><<<dim3(gb128, 4), 256, 0, stream>>>(
            aghi, aglo, W1hi + (size_t)l * 256 * HD, W1lo + (size_t)l * 256 * HD,
            b1 + l * 256, nullptr, zhi, zlo, N, nullptr);

        mgemm_k<256, HD, 0, 1, 0><<<dim3(gb128, 2), 256, 0, stream>>>(
            zhi, zlo, W2hi + (size_t)l * HD * 256, W2lo + (size_t)l * HD * 256,
            b2 + l * HD, (float*)d_out, nullptr, nullptr, N, stats + l * 256);

        bn_k<<<vblocks, 256, 0, stream>>>((const float*)d_out, stats + l * 256,
                                          bn_g + l * HD, bn_b + l * HD,
                                          (l < 2) ? h : (float*)d_out, total4, 1.f / N, (l < 2) ? 1 : 0);
    }
}